// Round 3
// baseline (277.787 us; speedup 1.0000x reference)
//
#include <hip/hip_runtime.h>
#include <hip/hip_cooperative_groups.h>
#include <math.h>

namespace cg = cooperative_groups;

#define BB 4
#define CC 128
#define HW 4096
// sqrt(10 * log2(e)) — folds 1/tau AND the exp->exp2 conversion into both
// normalized sides: sim' = sim * log2(e), so exp(sim) == exp2(sim').
#define SCF 3.798282565f

typedef short short8 __attribute__((ext_vector_type(8)));
typedef float f32x4 __attribute__((ext_vector_type(4)));

static __device__ inline unsigned short f2bf(float f) {
  // round-to-nearest-even fp32 -> bf16 (inputs are finite)
  unsigned int u = __float_as_uint(f);
  u += 0x7fffu + ((u >> 16) & 1u);
  return (unsigned short)(u >> 16);
}

static __device__ inline float fast_exp2(float x) {
#if __has_builtin(__builtin_amdgcn_exp2f)
  return __builtin_amdgcn_exp2f(x);
#else
  return exp2f(x);
#endif
}

// ============================================================================
// FUSED cooperative kernel: phase1 = normalize/pack, grid.sync, phase2 =
// B-resident MFMA GEMM + column expsum atomics, grid.sync, phase3 = loss.
// Saves two kernel-launch gaps vs the 3-kernel pipeline; phases are the
// verified bodies of k_prep / k_main / k_loss unchanged.
// LDS is a union: phase1 needs 36 KB, phase2 needs 64 KB -> 64 KB total,
// 2 blocks/CU, grid 512 = exactly co-resident (cooperative-launch legal).
// ============================================================================
__global__ __launch_bounds__(256, 2) void k_fused(
    const float* __restrict__ fA, const float* __restrict__ fB,
    unsigned short* __restrict__ fAn, unsigned short* __restrict__ fBn,
    float* __restrict__ diag, float* __restrict__ expsum,
    const float* __restrict__ mask, float* __restrict__ acc,
    float* __restrict__ out) {
  __shared__ union SM {
    struct { float sA[32 * 129]; float sB[32 * 129]; float red[3 * 256]; } p;
    unsigned short m[2][128 * 128];
    struct { float rn[4]; float rd[4]; } l;
  } sm;

  const int bid = blockIdx.x;          // 0..511
  const int tid = threadIdx.x;

  // ---------------- phase 1: normalize & pack (k_prep body) ----------------
  {
    const int b   = bid >> 7;
    const int n0  = (bid & 127) * 32;
    const int cR  = tid >> 5;            // 0..7
    const int n   = tid & 31;            // 0..31

    if (bid == 0 && tid == 0) { acc[0] = 0.f; acc[1] = 0.f; ((unsigned*)acc)[2] = 0u; }

    const float* pa = fA + (size_t)b * CC * HW + n0 + n;
    const float* pb = fB + (size_t)b * CC * HW + n0 + n;

    float ssa = 0.f, ssb = 0.f, dot = 0.f;
    #pragma unroll
    for (int it = 0; it < 16; ++it) {
      int c = it * 8 + cR;
      float va = pa[(size_t)c * HW];
      float vb = pb[(size_t)c * HW];
      sm.p.sA[n * 129 + c] = va;
      sm.p.sB[n * 129 + c] = vb;
      ssa = fmaf(va, va, ssa);
      ssb = fmaf(vb, vb, ssb);
      dot = fmaf(va, vb, dot);
    }
    sm.p.red[tid] = ssa; sm.p.red[256 + tid] = ssb; sm.p.red[512 + tid] = dot;
    __syncthreads();

    if (tid < 32) {
      float sa = 0.f, sb = 0.f, dt = 0.f;
      #pragma unroll
      for (int k = 0; k < 8; ++k) {
        sa += sm.p.red[k * 32 + tid];
        sb += sm.p.red[256 + k * 32 + tid];
        dt += sm.p.red[512 + k * 32 + tid];
      }
      float ia = 1.f / fmaxf(sqrtf(sa), 1e-12f);
      float ib = 1.f / fmaxf(sqrtf(sb), 1e-12f);
      int gidx = b * HW + n0 + tid;
      diag[gidx]   = dt * ia * ib * 10.f;   // true sim scale (1/tau)
      expsum[gidx] = 0.f;
      sm.p.red[tid]      = ia * SCF;   // sole reader/writer of these slots
      sm.p.red[32 + tid] = ib * SCF;
    }
    __syncthreads();

    #pragma unroll
    for (int r = 0; r < 2; ++r) {
      int L  = r * 256 + tid;
      int nn = L >> 4;                  // 0..31
      int q  = L & 15;                  // store position within row
      int c0 = (q ^ (nn & 7)) * 8;      // data chunk (swizzle)
      size_t base = ((size_t)b * HW + n0 + nn) * 128 + q * 8;
      {
        float sc = sm.p.red[nn];
        const float* s = &sm.p.sA[nn * 129 + c0];
        uint4 v;
        v.x = f2bf(s[0]*sc) | ((unsigned)f2bf(s[1]*sc) << 16);
        v.y = f2bf(s[2]*sc) | ((unsigned)f2bf(s[3]*sc) << 16);
        v.z = f2bf(s[4]*sc) | ((unsigned)f2bf(s[5]*sc) << 16);
        v.w = f2bf(s[6]*sc) | ((unsigned)f2bf(s[7]*sc) << 16);
        *(uint4*)(fAn + base) = v;
      }
      {
        float sc = sm.p.red[32 + nn];
        const float* s = &sm.p.sB[nn * 129 + c0];
        uint4 v;
        v.x = f2bf(s[0]*sc) | ((unsigned)f2bf(s[1]*sc) << 16);
        v.y = f2bf(s[2]*sc) | ((unsigned)f2bf(s[3]*sc) << 16);
        v.z = f2bf(s[4]*sc) | ((unsigned)f2bf(s[5]*sc) << 16);
        v.w = f2bf(s[6]*sc) | ((unsigned)f2bf(s[7]*sc) << 16);
        *(uint4*)(fBn + base) = v;
      }
    }
  }

  __threadfence();           // agent-scope release: L2 writeback of fAn/fBn
  cg::this_grid().sync();

  // ---------------- phase 2: GEMM + column expsum (k_main body) ------------
  {
    const int x   = bid & 7;                   // XCD
    const int t   = bid >> 3;                  // 0..63
    const int b   = x & 3;
    const int nq  = (x >> 2) | ((t & 1) << 1); // 0..3
    const int mt  = t >> 1;                    // 0..31
    const int m0  = mt * 128;
    const int nbase = nq * 1024;

    const int wv   = tid >> 6;
    const int lane = tid & 63;
    const int ml   = lane & 15;
    const int g    = lane >> 4;
    const int wn   = (wv & 1) * 64;    // wave n-offset within chunk
    const int wm   = (wv >> 1) * 64;   // wave m-offset within tile

    // Prologue: stage B-tile into buf1 and A-chunk 0 into buf0 concurrently.
    const unsigned short* gB  = fBn + ((size_t)b * HW + m0) * 128;
    const unsigned short* gA0 = fAn + ((size_t)b * HW + nbase) * 128;
    #pragma unroll
    for (int r = 0; r < 8; ++r) {
      int L = r * 256 + tid;
      __builtin_amdgcn_global_load_lds(
          (const __attribute__((address_space(1))) unsigned int*)(gB + (size_t)L * 8),
          (__attribute__((address_space(3))) unsigned int*)(sm.m[1] + L * 8), 16, 0, 0);
      __builtin_amdgcn_global_load_lds(
          (const __attribute__((address_space(1))) unsigned int*)(gA0 + (size_t)L * 8),
          (__attribute__((address_space(3))) unsigned int*)(sm.m[0] + L * 8), 16, 0, 0);
    }
    __syncthreads();   // both prologue stages complete

    // Hoist B fragments into registers (invariant across all 8 iters).
    short8 bfr[4][4];  // [kc][s]
    #pragma unroll
    for (int kc = 0; kc < 4; ++kc) {
      int q = kc * 4 + g;
      #pragma unroll
      for (int s = 0; s < 4; ++s) {
        int nb = wm + s * 16 + ml;
        bfr[kc][s] = *(const short8*)(sm.m[1] + nb * 128 + ((q ^ (nb & 7)) * 8));
      }
    }
    __syncthreads();   // all waves done reading B from buf1 -> buf1 reusable

    float colAcc[4] = {0.f, 0.f, 0.f, 0.f};

    #pragma unroll 2
    for (int it = 0; it < 8; ++it) {
      // Issue next chunk's staging FIRST (lands during this iteration's MFMAs).
      if (it < 7) {
        const unsigned short* gA = fAn + ((size_t)b * HW + nbase + (it + 1) * 128) * 128;
        unsigned short* dst = sm.m[(it + 1) & 1];
        #pragma unroll
        for (int r = 0; r < 8; ++r) {
          int L = r * 256 + tid;
          __builtin_amdgcn_global_load_lds(
              (const __attribute__((address_space(1))) unsigned int*)(gA + (size_t)L * 8),
              (__attribute__((address_space(3))) unsigned int*)(dst + L * 8), 16, 0, 0);
        }
      }

      const unsigned short* src = sm.m[it & 1];
      f32x4 acc4[4][4] = {};             // [n_sub][m_sub]
      #pragma unroll
      for (int kc = 0; kc < 4; ++kc) {
        short8 af[4];
        int q = kc * 4 + g;
        #pragma unroll
        for (int s = 0; s < 4; ++s) {
          int na = wn + s * 16 + ml;
          af[s] = *(const short8*)(src + na * 128 + ((q ^ (na & 7)) * 8));
        }
        #pragma unroll
        for (int i = 0; i < 4; ++i)
          #pragma unroll
          for (int j = 0; j < 4; ++j)
            acc4[i][j] = __builtin_amdgcn_mfma_f32_16x16x32_bf16(af[i], bfr[kc][j], acc4[i][j], 0, 0, 0);
      }
      // epilogue: accumulate exp2(sim') per column (C layout: col=lane&15,
      // row=g*4+reg). |sim'| <= 14.43 -> exp2 in [4.6e-5, 2.2e4], no shift.
      #pragma unroll
      for (int j = 0; j < 4; ++j) {
        float e = 0.f;
        #pragma unroll
        for (int i = 0; i < 4; ++i)
          #pragma unroll
          for (int r = 0; r < 4; ++r)
            e += fast_exp2(acc4[i][j][r]);
        colAcc[j] += e;
      }

      __syncthreads();   // drains the STAGE issued above; orders buffer reuse
    }

    #pragma unroll
    for (int j = 0; j < 4; ++j) {
      float e = colAcc[j];
      e += __shfl_xor(e, 16, 64);
      e += __shfl_xor(e, 32, 64);
      if (lane < 16)
        atomicAdd(&expsum[(size_t)b * HW + m0 + wm + j * 16 + lane], e);
    }
  }

  __threadfence();           // release expsum atomaics/diag before readers
  cg::this_grid().sync();

  // ---------------- phase 3: masked-mean loss (k_loss body, 64 blocks) -----
  __syncthreads();           // smem handoff (phase2 reads -> phase3 writes)
  if (bid < 64) {
    const int i = bid * 256 + tid;                // 64*256 = 16384
    float lse = __logf(expsum[i]);                // ln(sum exp(sim))
    float mv  = mask[i];
    float num = mv * (lse - diag[i]);
    #pragma unroll
    for (int off = 32; off; off >>= 1) {
      num += __shfl_down(num, off, 64);
      mv  += __shfl_down(mv,  off, 64);
    }
    const int lane = tid & 63, wv = tid >> 6;
    if (lane == 0) { sm.l.rn[wv] = num; sm.l.rd[wv] = mv; }
    __syncthreads();
    if (tid == 0) {
      float n = sm.l.rn[0] + sm.l.rn[1] + sm.l.rn[2] + sm.l.rn[3];
      float d = sm.l.rd[0] + sm.l.rd[1] + sm.l.rd[2] + sm.l.rd[3];
      atomicAdd(&acc[0], n);
      atomicAdd(&acc[1], d);
      __threadfence();
      unsigned prev = atomicAdd((unsigned*)(acc + 2), 1u);
      if (prev == 63u) {   // last block: all partials visible (fence-ordered)
        float fn = atomicAdd(&acc[0], 0.f);
        float fd = atomicAdd(&acc[1], 0.f);
        out[0] = fn / (fd + 1e-6f);
      }
    }
  }
}

// ============================================================================
// Fallback 3-kernel pipeline (identical logic) — used only if the cooperative
// launch cannot be enqueued (e.g. capture refuses cooperative nodes).
// ============================================================================
__global__ __launch_bounds__(256) void k_prep(const float* __restrict__ fA,
                                              const float* __restrict__ fB,
                                              unsigned short* __restrict__ fAn,
                                              unsigned short* __restrict__ fBn,
                                              float* __restrict__ diag,
                                              float* __restrict__ expsum,
                                              float* __restrict__ acc) {
  __shared__ float sA[32 * 129];
  __shared__ float sB[32 * 129];
  __shared__ float red[3 * 256];

  const int bid = blockIdx.x;
  const int b   = bid >> 7;
  const int n0  = (bid & 127) * 32;
  const int tid = threadIdx.x;
  const int cR  = tid >> 5;
  const int n   = tid & 31;

  if (bid == 0 && tid == 0) { acc[0] = 0.f; acc[1] = 0.f; ((unsigned*)acc)[2] = 0u; }

  const float* pa = fA + (size_t)b * CC * HW + n0 + n;
  const float* pb = fB + (size_t)b * CC * HW + n0 + n;

  float ssa = 0.f, ssb = 0.f, dot = 0.f;
  #pragma unroll
  for (int it = 0; it < 16; ++it) {
    int c = it * 8 + cR;
    float va = pa[(size_t)c * HW];
    float vb = pb[(size_t)c * HW];
    sA[n * 129 + c] = va;
    sB[n * 129 + c] = vb;
    ssa = fmaf(va, va, ssa);
    ssb = fmaf(vb, vb, ssb);
    dot = fmaf(va, vb, dot);
  }
  red[tid] = ssa; red[256 + tid] = ssb; red[512 + tid] = dot;
  __syncthreads();

  if (tid < 32) {
    float sa = 0.f, sb = 0.f, dt = 0.f;
    #pragma unroll
    for (int k = 0; k < 8; ++k) {
      sa += red[k * 32 + tid];
      sb += red[256 + k * 32 + tid];
      dt += red[512 + k * 32 + tid];
    }
    float ia = 1.f / fmaxf(sqrtf(sa), 1e-12f);
    float ib = 1.f / fmaxf(sqrtf(sb), 1e-12f);
    int gidx = b * HW + n0 + tid;
    diag[gidx]   = dt * ia * ib * 10.f;
    expsum[gidx] = 0.f;
    red[tid]      = ia * SCF;
    red[32 + tid] = ib * SCF;
  }
  __syncthreads();

  #pragma unroll
  for (int r = 0; r < 2; ++r) {
    int L  = r * 256 + tid;
    int nn = L >> 4;
    int q  = L & 15;
    int c0 = (q ^ (nn & 7)) * 8;
    size_t base = ((size_t)b * HW + n0 + nn) * 128 + q * 8;
    {
      float sc = red[nn];
      const float* s = &sA[nn * 129 + c0];
      uint4 v;
      v.x = f2bf(s[0]*sc) | ((unsigned)f2bf(s[1]*sc) << 16);
      v.y = f2bf(s[2]*sc) | ((unsigned)f2bf(s[3]*sc) << 16);
      v.z = f2bf(s[4]*sc) | ((unsigned)f2bf(s[5]*sc) << 16);
      v.w = f2bf(s[6]*sc) | ((unsigned)f2bf(s[7]*sc) << 16);
      *(uint4*)(fAn + base) = v;
    }
    {
      float sc = red[32 + nn];
      const float* s = &sB[nn * 129 + c0];
      uint4 v;
      v.x = f2bf(s[0]*sc) | ((unsigned)f2bf(s[1]*sc) << 16);
      v.y = f2bf(s[2]*sc) | ((unsigned)f2bf(s[3]*sc) << 16);
      v.z = f2bf(s[4]*sc) | ((unsigned)f2bf(s[5]*sc) << 16);
      v.w = f2bf(s[6]*sc) | ((unsigned)f2bf(s[7]*sc) << 16);
      *(uint4*)(fBn + base) = v;
    }
  }
}

__global__ __launch_bounds__(256, 2) void k_main(const unsigned short* __restrict__ fAn,
                                                 const unsigned short* __restrict__ fBn,
                                                 float* __restrict__ expsum) {
  __shared__ unsigned short sA[2][128 * 128];

  const int bid = blockIdx.x;
  const int x   = bid & 7;
  const int t   = bid >> 3;
  const int b   = x & 3;
  const int nq  = (x >> 2) | ((t & 1) << 1);
  const int mt  = t >> 1;
  const int m0  = mt * 128;
  const int nbase = nq * 1024;
  const int tid = threadIdx.x;

  const int wv   = tid >> 6;
  const int lane = tid & 63;
  const int ml   = lane & 15;
  const int g    = lane >> 4;
  const int wn   = (wv & 1) * 64;
  const int wm   = (wv >> 1) * 64;

  const unsigned short* gB  = fBn + ((size_t)b * HW + m0) * 128;
  const unsigned short* gA0 = fAn + ((size_t)b * HW + nbase) * 128;
  #pragma unroll
  for (int r = 0; r < 8; ++r) {
    int L = r * 256 + tid;
    __builtin_amdgcn_global_load_lds(
        (const __attribute__((address_space(1))) unsigned int*)(gB + (size_t)L * 8),
        (__attribute__((address_space(3))) unsigned int*)(sA[1] + L * 8), 16, 0, 0);
    __builtin_amdgcn_global_load_lds(
        (const __attribute__((address_space(1))) unsigned int*)(gA0 + (size_t)L * 8),
        (__attribute__((address_space(3))) unsigned int*)(sA[0] + L * 8), 16, 0, 0);
  }
  __syncthreads();

  short8 bfr[4][4];
  #pragma unroll
  for (int kc = 0; kc < 4; ++kc) {
    int q = kc * 4 + g;
    #pragma unroll
    for (int s = 0; s < 4; ++s) {
      int nb = wm + s * 16 + ml;
      bfr[kc][s] = *(const short8*)(sA[1] + nb * 128 + ((q ^ (nb & 7)) * 8));
    }
  }
  __syncthreads();

  float colAcc[4] = {0.f, 0.f, 0.f, 0.f};

  #pragma unroll 2
  for (int it = 0; it < 8; ++it) {
    if (it < 7) {
      const unsigned short* gA = fAn + ((size_t)b * HW + nbase + (it + 1) * 128) * 128;
      unsigned short* dst = sA[(it + 1) & 1];
      #pragma unroll
      for (int r = 0; r < 8; ++r) {
        int L = r * 256 + tid;
        __builtin_amdgcn_global_load_lds(
            (const __attribute__((address_space(1))) unsigned int*)(gA + (size_t)L * 8),
            (__attribute__((address_space(3))) unsigned int*)(dst + L * 8), 16, 0, 0);
      }
    }

    const unsigned short* src = sA[it & 1];
    f32x4 acc4[4][4] = {};
    #pragma unroll
    for (int kc = 0; kc < 4; ++kc) {
      short8 af[4];
      int q = kc * 4 + g;
      #pragma unroll
      for (int s = 0; s < 4; ++s) {
        int na = wn + s * 16 + ml;
        af[s] = *(const short8*)(src + na * 128 + ((q ^ (na & 7)) * 8));
      }
      #pragma unroll
      for (int i = 0; i < 4; ++i)
        #pragma unroll
        for (int j = 0; j < 4; ++j)
          acc4[i][j] = __builtin_amdgcn_mfma_f32_16x16x32_bf16(af[i], bfr[kc][j], acc4[i][j], 0, 0, 0);
    }
    #pragma unroll
    for (int j = 0; j < 4; ++j) {
      float e = 0.f;
      #pragma unroll
      for (int i = 0; i < 4; ++i)
        #pragma unroll
        for (int r = 0; r < 4; ++r)
          e += fast_exp2(acc4[i][j][r]);
      colAcc[j] += e;
    }

    __syncthreads();
  }

  #pragma unroll
  for (int j = 0; j < 4; ++j) {
    float e = colAcc[j];
    e += __shfl_xor(e, 16, 64);
    e += __shfl_xor(e, 32, 64);
    if (lane < 16)
      atomicAdd(&expsum[(size_t)b * HW + m0 + wm + j * 16 + lane], e);
  }
}

__global__ __launch_bounds__(256) void k_loss(const float* __restrict__ diag,
                                              const float* __restrict__ expsum,
                                              const float* __restrict__ mask,
                                              float* __restrict__ acc,
                                              float* __restrict__ out) {
  __shared__ float rn[4], rd[4];
  const int i = blockIdx.x * 256 + threadIdx.x;
  float lse = __logf(expsum[i]);
  float mv  = mask[i];
  float num = mv * (lse - diag[i]);
  #pragma unroll
  for (int off = 32; off; off >>= 1) {
    num += __shfl_down(num, off, 64);
    mv  += __shfl_down(mv,  off, 64);
  }
  const int lane = threadIdx.x & 63, wv = threadIdx.x >> 6;
  if (lane == 0) { rn[wv] = num; rd[wv] = mv; }
  __syncthreads();
  if (threadIdx.x == 0) {
    float n = rn[0] + rn[1] + rn[2] + rn[3];
    float d = rd[0] + rd[1] + rd[2] + rd[3];
    atomicAdd(&acc[0], n);
    atomicAdd(&acc[1], d);
    __threadfence();
    unsigned prev = atomicAdd((unsigned*)(acc + 2), 1u);
    if (prev == 63u) {
      float fn = atomicAdd(&acc[0], 0.f);
      float fd = atomicAdd(&acc[1], 0.f);
      out[0] = fn / (fd + 1e-6f);
    }
  }
}

extern "C" void kernel_launch(void* const* d_in, const int* in_sizes, int n_in,
                              void* d_out, int out_size, void* d_ws, size_t ws_size,
                              hipStream_t stream) {
  const float* feat_A = (const float*)d_in[0];
  const float* feat_B = (const float*)d_in[1];
  // d_in[2] = H_mat : unused by the reference computation
  const float* vmask  = (const float*)d_in[3];

  unsigned short* fAn = (unsigned short*)d_ws;            // 4 MB bf16 [b][n][c] swizzled
  unsigned short* fBn = fAn + (size_t)BB * HW * CC;       // 4 MB
  float* diag   = (float*)(fBn + (size_t)BB * HW * CC);   // 64 KB
  float* expsum = diag + BB * HW;                         // 64 KB
  float* acc    = expsum + BB * HW;                       // 12 B: num, den, ctr
  float* out    = (float*)d_out;

  void* args[] = {(void*)&feat_A, (void*)&feat_B, (void*)&fAn, (void*)&fBn,
                  (void*)&diag, (void*)&expsum, (void*)&vmask, (void*)&acc,
                  (void*)&out};
  hipError_t e = hipLaunchCooperativeKernel((void*)k_fused, dim3(512), dim3(256),
                                            args, 0, stream);
  if (e != hipSuccess) {
    // Fallback: identical 3-kernel pipeline (kernel boundaries = grid syncs).
    k_prep<<<512, 256, 0, stream>>>(feat_A, feat_B, fAn, fBn, diag, expsum, acc);
    k_main<<<512, 256, 0, stream>>>(fAn, fBn, expsum);
    k_loss<<<64,  256, 0, stream>>>(diag, expsum, vmask, acc, out);
  }
}

// Round 4
// 105.545 us; speedup vs baseline: 2.6319x; 2.6319x over previous
//
#include <hip/hip_runtime.h>
#include <math.h>

#define BB 4
#define CC 128
#define HW 4096
// sqrt(10 * log2(e)) — folds 1/tau AND the exp->exp2 conversion into both
// normalized sides: sim' = sim * log2(e), so exp(sim) == exp2(sim').
#define SCF 3.798282565f

typedef short short8 __attribute__((ext_vector_type(8)));
typedef float f32x4 __attribute__((ext_vector_type(4)));

static __device__ inline unsigned short f2bf(float f) {
  // round-to-nearest-even fp32 -> bf16 (inputs are finite)
  unsigned int u = __float_as_uint(f);
  u += 0x7fffu + ((u >> 16) & 1u);
  return (unsigned short)(u >> 16);
}

static __device__ inline float fast_exp2(float x) {
#if __has_builtin(__builtin_amdgcn_exp2f)
  return __builtin_amdgcn_exp2f(x);
#else
  return exp2f(x);
#endif
}

// K1: per 32-position tile: inv-norms of A and B, fp32 diagonal similarity,
// zero expsum + finish-counter, and write bf16 normalized*SCF features
// transposed to [b][pos][c] with XOR-swizzled 16B chunks (position q holds
// data chunk q^(n&7)) so k_main's global_load_lds staging is an identity copy
// while MFMA fragment ds_reads stay 2-way-conflict (free).
__global__ __launch_bounds__(256) void k_prep(const float* __restrict__ fA,
                                              const float* __restrict__ fB,
                                              unsigned short* __restrict__ fAn,
                                              unsigned short* __restrict__ fBn,
                                              float* __restrict__ diag,
                                              float* __restrict__ expsum,
                                              float* __restrict__ acc) {
  __shared__ float sA[32 * 129];
  __shared__ float sB[32 * 129];
  __shared__ float red[3 * 256];

  const int bid = blockIdx.x;          // 0..511 : b*128 + tile
  const int b   = bid >> 7;
  const int n0  = (bid & 127) * 32;
  const int tid = threadIdx.x;
  const int cR  = tid >> 5;            // 0..7
  const int n   = tid & 31;            // 0..31

  if (bid == 0 && tid == 0) ((unsigned*)acc)[2] = 0u;   // finish counter

  const float* pa = fA + (size_t)b * CC * HW + n0 + n;
  const float* pb = fB + (size_t)b * CC * HW + n0 + n;

  float ssa = 0.f, ssb = 0.f, dot = 0.f;
  #pragma unroll
  for (int it = 0; it < 16; ++it) {
    int c = it * 8 + cR;
    float va = pa[(size_t)c * HW];
    float vb = pb[(size_t)c * HW];
    sA[n * 129 + c] = va;
    sB[n * 129 + c] = vb;
    ssa = fmaf(va, va, ssa);
    ssb = fmaf(vb, vb, ssb);
    dot = fmaf(va, vb, dot);
  }
  red[tid] = ssa; red[256 + tid] = ssb; red[512 + tid] = dot;
  __syncthreads();

  if (tid < 32) {
    float sa = 0.f, sb = 0.f, dt = 0.f;
    #pragma unroll
    for (int k = 0; k < 8; ++k) {
      sa += red[k * 32 + tid];
      sb += red[256 + k * 32 + tid];
      dt += red[512 + k * 32 + tid];
    }
    float ia = 1.f / fmaxf(sqrtf(sa), 1e-12f);
    float ib = 1.f / fmaxf(sqrtf(sb), 1e-12f);
    int gidx = b * HW + n0 + tid;
    diag[gidx]   = dt * ia * ib * 10.f;   // true sim scale (1/tau)
    expsum[gidx] = 0.f;
    red[tid]      = ia * SCF;   // sole reader/writer of these slots
    red[32 + tid] = ib * SCF;
  }
  __syncthreads();

  #pragma unroll
  for (int r = 0; r < 2; ++r) {
    int L  = r * 256 + tid;
    int nn = L >> 4;                  // 0..31
    int q  = L & 15;                  // store position within row
    int c0 = (q ^ (nn & 7)) * 8;      // data chunk (swizzle)
    size_t base = ((size_t)b * HW + n0 + nn) * 128 + q * 8;
    {
      float sc = red[nn];
      const float* s = &sA[nn * 129 + c0];
      uint4 v;
      v.x = f2bf(s[0]*sc) | ((unsigned)f2bf(s[1]*sc) << 16);
      v.y = f2bf(s[2]*sc) | ((unsigned)f2bf(s[3]*sc) << 16);
      v.z = f2bf(s[4]*sc) | ((unsigned)f2bf(s[5]*sc) << 16);
      v.w = f2bf(s[6]*sc) | ((unsigned)f2bf(s[7]*sc) << 16);
      *(uint4*)(fAn + base) = v;
    }
    {
      float sc = red[32 + nn];
      const float* s = &sB[nn * 129 + c0];
      uint4 v;
      v.x = f2bf(s[0]*sc) | ((unsigned)f2bf(s[1]*sc) << 16);
      v.y = f2bf(s[2]*sc) | ((unsigned)f2bf(s[3]*sc) << 16);
      v.z = f2bf(s[4]*sc) | ((unsigned)f2bf(s[5]*sc) << 16);
      v.w = f2bf(s[6]*sc) | ((unsigned)f2bf(s[7]*sc) << 16);
      *(uint4*)(fBn + base) = v;
    }
  }
}

// K2: B-resident MFMA GEMM + fused loss finish (last-block-done pattern).
//  - B fragments hoisted to registers once (64 VGPR); A chunk double-buffered
//    in LDS, STAGE(it+1) issued before compute(it), one barrier/iter.
//  - After a block's expsum atomics: __syncthreads (drains vmcnt -> atomics
//    globally performed), __threadfence (release), ctr atomicAdd. The block
//    seeing prev==511 runs the loss reduction alone: agent-scope atomic loads
//    of expsum (L1-bypass; other XCDs' atomics visible), plain diag/mask
//    loads (produced before this kernel), block-reduce, write out[0].
//  - Replaces the separate k_loss dispatch: one fewer launch + gap.
__global__ __launch_bounds__(256, 2) void k_main(const unsigned short* __restrict__ fAn,
                                                 const unsigned short* __restrict__ fBn,
                                                 float* __restrict__ expsum,
                                                 const float* __restrict__ diag,
                                                 const float* __restrict__ mask,
                                                 float* __restrict__ acc,
                                                 float* __restrict__ out) {
  __shared__ unsigned short sA[2][128 * 128];   // 64 KB double-buffered A chunk

  const int bid = blockIdx.x;                // 0..511
  const int x   = bid & 7;                   // XCD
  const int t   = bid >> 3;                  // 0..63
  const int b   = x & 3;
  const int nq  = (x >> 2) | ((t & 1) << 1); // 0..3
  const int mt  = t >> 1;                    // 0..31
  const int m0  = mt * 128;
  const int nbase = nq * 1024;
  const int tid = threadIdx.x;

  const int wv   = tid >> 6;
  const int lane = tid & 63;
  const int ml   = lane & 15;
  const int g    = lane >> 4;
  const int wn   = (wv & 1) * 64;    // wave n-offset within chunk
  const int wm   = (wv >> 1) * 64;   // wave m-offset within tile

  // Prologue: stage B-tile into buf1 and A-chunk 0 into buf0 concurrently.
  const unsigned short* gB  = fBn + ((size_t)b * HW + m0) * 128;
  const unsigned short* gA0 = fAn + ((size_t)b * HW + nbase) * 128;
  #pragma unroll
  for (int r = 0; r < 8; ++r) {
    int L = r * 256 + tid;
    __builtin_amdgcn_global_load_lds(
        (const __attribute__((address_space(1))) unsigned int*)(gB + (size_t)L * 8),
        (__attribute__((address_space(3))) unsigned int*)(sA[1] + L * 8), 16, 0, 0);
    __builtin_amdgcn_global_load_lds(
        (const __attribute__((address_space(1))) unsigned int*)(gA0 + (size_t)L * 8),
        (__attribute__((address_space(3))) unsigned int*)(sA[0] + L * 8), 16, 0, 0);
  }
  __syncthreads();   // both prologue stages complete

  // Hoist B fragments into registers (invariant across all 8 iters).
  short8 bfr[4][4];  // [kc][s]
  #pragma unroll
  for (int kc = 0; kc < 4; ++kc) {
    int q = kc * 4 + g;
    #pragma unroll
    for (int s = 0; s < 4; ++s) {
      int nb = wm + s * 16 + ml;
      bfr[kc][s] = *(const short8*)(sA[1] + nb * 128 + ((q ^ (nb & 7)) * 8));
    }
  }
  __syncthreads();   // all waves done reading B from buf1 -> buf1 reusable

  float colAcc[4] = {0.f, 0.f, 0.f, 0.f};

  #pragma unroll 2
  for (int it = 0; it < 8; ++it) {
    // Issue next chunk's staging FIRST (lands during this iteration's MFMAs).
    if (it < 7) {
      const unsigned short* gA = fAn + ((size_t)b * HW + nbase + (it + 1) * 128) * 128;
      unsigned short* dst = sA[(it + 1) & 1];
      #pragma unroll
      for (int r = 0; r < 8; ++r) {
        int L = r * 256 + tid;
        __builtin_amdgcn_global_load_lds(
            (const __attribute__((address_space(1))) unsigned int*)(gA + (size_t)L * 8),
            (__attribute__((address_space(3))) unsigned int*)(dst + L * 8), 16, 0, 0);
      }
    }

    const unsigned short* src = sA[it & 1];
    f32x4 acc4[4][4] = {};             // [n_sub][m_sub]
    #pragma unroll
    for (int kc = 0; kc < 4; ++kc) {
      short8 af[4];
      int q = kc * 4 + g;
      #pragma unroll
      for (int s = 0; s < 4; ++s) {
        int na = wn + s * 16 + ml;
        af[s] = *(const short8*)(src + na * 128 + ((q ^ (na & 7)) * 8));
      }
      #pragma unroll
      for (int i = 0; i < 4; ++i)
        #pragma unroll
        for (int j = 0; j < 4; ++j)
          acc4[i][j] = __builtin_amdgcn_mfma_f32_16x16x32_bf16(af[i], bfr[kc][j], acc4[i][j], 0, 0, 0);
    }
    // epilogue: accumulate exp2(sim') per column (C layout: col=lane&15,
    // row=g*4+reg). |sim'| <= 14.43 -> exp2 in [4.6e-5, 2.2e4], no shift.
    #pragma unroll
    for (int j = 0; j < 4; ++j) {
      float e = 0.f;
      #pragma unroll
      for (int i = 0; i < 4; ++i)
        #pragma unroll
        for (int r = 0; r < 4; ++r)
          e += fast_exp2(acc4[i][j][r]);
      colAcc[j] += e;
    }

    __syncthreads();   // drains the STAGE issued above; orders buffer reuse
  }

  #pragma unroll
  for (int j = 0; j < 4; ++j) {
    float e = colAcc[j];
    e += __shfl_xor(e, 16, 64);
    e += __shfl_xor(e, 32, 64);
    if (lane < 16)
      atomicAdd(&expsum[(size_t)b * HW + m0 + wm + j * 16 + lane], e);
  }

  // ---- last-block-done loss finish ----
  __syncthreads();   // all waves' expsum atomics drained (vmcnt(0) at barrier)
  int* flag = (int*)&sA[0][0];
  if (tid == 0) {
    __threadfence();                           // release our atomics
    unsigned prev = atomicAdd((unsigned*)acc + 2, 1u);
    flag[0] = (prev == 511u) ? 1 : 0;
    if (flag[0]) __threadfence();              // acquire: others' ctr incs ordered their atomics
  }
  __syncthreads();
  if (flag[0]) {
    float num = 0.f, den = 0.f;
    #pragma unroll 4
    for (int r = 0; r < 64; ++r) {
      int i = r * 256 + tid;                   // 16384 = 64*256
      float es = __hip_atomic_load(&expsum[i], __ATOMIC_RELAXED,
                                   __HIP_MEMORY_SCOPE_AGENT);
      float mv = mask[i];
      num = fmaf(mv, __logf(es) - diag[i], num);
      den += mv;
    }
    #pragma unroll
    for (int off = 32; off; off >>= 1) {
      num += __shfl_down(num, off, 64);
      den += __shfl_down(den, off, 64);
    }
    float* red = (float*)&sA[0][0] + 16;       // clear of flag slot
    if (lane == 0) { red[wv * 2] = num; red[wv * 2 + 1] = den; }
    __syncthreads();
    if (tid == 0) {
      float n = red[0] + red[2] + red[4] + red[6];
      float d = red[1] + red[3] + red[5] + red[7];
      out[0] = n / (d + 1e-6f);
    }
  }
}

extern "C" void kernel_launch(void* const* d_in, const int* in_sizes, int n_in,
                              void* d_out, int out_size, void* d_ws, size_t ws_size,
                              hipStream_t stream) {
  const float* feat_A = (const float*)d_in[0];
  const float* feat_B = (const float*)d_in[1];
  // d_in[2] = H_mat : unused by the reference computation
  const float* vmask  = (const float*)d_in[3];

  unsigned short* fAn = (unsigned short*)d_ws;            // 4 MB bf16 [b][n][c] swizzled
  unsigned short* fBn = fAn + (size_t)BB * HW * CC;       // 4 MB
  float* diag   = (float*)(fBn + (size_t)BB * HW * CC);   // 64 KB
  float* expsum = diag + BB * HW;                         // 64 KB
  float* acc    = expsum + BB * HW;                       // 12 B: num, den, ctr
  float* out    = (float*)d_out;

  k_prep<<<512, 256, 0, stream>>>(feat_A, feat_B, fAn, fBn, diag, expsum, acc);
  k_main<<<512, 256, 0, stream>>>(fAn, fBn, expsum, diag, vmask, acc, out);
}

// Round 5
// 96.451 us; speedup vs baseline: 2.8801x; 1.0943x over previous
//
#include <hip/hip_runtime.h>
#include <math.h>

#define BB 4
#define CC 128
#define HW 4096
// sqrt(10 * log2(e)) — folds 1/tau AND the exp->exp2 conversion into both
// normalized sides: sim' = sim * log2(e), so exp(sim) == exp2(sim').
#define SCF 3.798282565f

typedef short short8 __attribute__((ext_vector_type(8)));
typedef float f32x4 __attribute__((ext_vector_type(4)));

static __device__ inline unsigned short f2bf(float f) {
  // round-to-nearest-even fp32 -> bf16 (inputs are finite)
  unsigned int u = __float_as_uint(f);
  u += 0x7fffu + ((u >> 16) & 1u);
  return (unsigned short)(u >> 16);
}

static __device__ inline float fast_exp2(float x) {
#if __has_builtin(__builtin_amdgcn_exp2f)
  return __builtin_amdgcn_exp2f(x);
#else
  return exp2f(x);
#endif
}

// K1: per 32-position tile: inv-norms of A and B, fp32 diagonal similarity,
// zero scalar accumulators, and write bf16 normalized*SCF features
// transposed to [b][pos][c] with XOR-swizzled 16B chunks (position q holds
// data chunk q^(n&7)) so k_main's global_load_lds staging is an identity copy
// while MFMA fragment ds_reads stay 2-way-conflict (free).
// NOTE: no expsum zeroing needed anymore — k_main writes exclusive psum slots.
__global__ __launch_bounds__(256) void k_prep(const float* __restrict__ fA,
                                              const float* __restrict__ fB,
                                              unsigned short* __restrict__ fAn,
                                              unsigned short* __restrict__ fBn,
                                              float* __restrict__ diag,
                                              float* __restrict__ acc) {
  __shared__ float sA[32 * 129];
  __shared__ float sB[32 * 129];
  __shared__ float red[3 * 256];

  const int bid = blockIdx.x;          // 0..511 : b*128 + tile
  const int b   = bid >> 7;
  const int n0  = (bid & 127) * 32;
  const int tid = threadIdx.x;
  const int cR  = tid >> 5;            // 0..7
  const int n   = tid & 31;            // 0..31

  if (bid == 0 && tid == 0) { acc[0] = 0.f; acc[1] = 0.f; ((unsigned*)acc)[2] = 0u; }

  const float* pa = fA + (size_t)b * CC * HW + n0 + n;
  const float* pb = fB + (size_t)b * CC * HW + n0 + n;

  float ssa = 0.f, ssb = 0.f, dot = 0.f;
  #pragma unroll
  for (int it = 0; it < 16; ++it) {
    int c = it * 8 + cR;
    float va = pa[(size_t)c * HW];
    float vb = pb[(size_t)c * HW];
    sA[n * 129 + c] = va;
    sB[n * 129 + c] = vb;
    ssa = fmaf(va, va, ssa);
    ssb = fmaf(vb, vb, ssb);
    dot = fmaf(va, vb, dot);
  }
  red[tid] = ssa; red[256 + tid] = ssb; red[512 + tid] = dot;
  __syncthreads();

  if (tid < 32) {
    float sa = 0.f, sb = 0.f, dt = 0.f;
    #pragma unroll
    for (int k = 0; k < 8; ++k) {
      sa += red[k * 32 + tid];
      sb += red[256 + k * 32 + tid];
      dt += red[512 + k * 32 + tid];
    }
    float ia = 1.f / fmaxf(sqrtf(sa), 1e-12f);
    float ib = 1.f / fmaxf(sqrtf(sb), 1e-12f);
    int gidx = b * HW + n0 + tid;
    diag[gidx]   = dt * ia * ib * 10.f;   // true sim scale (1/tau)
    red[tid]      = ia * SCF;   // sole reader/writer of these slots
    red[32 + tid] = ib * SCF;
  }
  __syncthreads();

  #pragma unroll
  for (int r = 0; r < 2; ++r) {
    int L  = r * 256 + tid;
    int nn = L >> 4;                  // 0..31
    int q  = L & 15;                  // store position within row
    int c0 = (q ^ (nn & 7)) * 8;      // data chunk (swizzle)
    size_t base = ((size_t)b * HW + n0 + nn) * 128 + q * 8;
    {
      float sc = red[nn];
      const float* s = &sA[nn * 129 + c0];
      uint4 v;
      v.x = f2bf(s[0]*sc) | ((unsigned)f2bf(s[1]*sc) << 16);
      v.y = f2bf(s[2]*sc) | ((unsigned)f2bf(s[3]*sc) << 16);
      v.z = f2bf(s[4]*sc) | ((unsigned)f2bf(s[5]*sc) << 16);
      v.w = f2bf(s[6]*sc) | ((unsigned)f2bf(s[7]*sc) << 16);
      *(uint4*)(fAn + base) = v;
    }
    {
      float sc = red[32 + nn];
      const float* s = &sB[nn * 129 + c0];
      uint4 v;
      v.x = f2bf(s[0]*sc) | ((unsigned)f2bf(s[1]*sc) << 16);
      v.y = f2bf(s[2]*sc) | ((unsigned)f2bf(s[3]*sc) << 16);
      v.z = f2bf(s[4]*sc) | ((unsigned)f2bf(s[5]*sc) << 16);
      v.w = f2bf(s[6]*sc) | ((unsigned)f2bf(s[7]*sc) << 16);
      *(uint4*)(fBn + base) = v;
    }
  }
}

// K2: B-resident MFMA GEMM (verified R1 structure):
//  - B fragments hoisted to registers once (64 VGPR); A chunk double-buffered
//    in LDS (2x32 KB); STAGE(it+1) issued BEFORE compute(it); one barrier/iter.
//  - Column sums of exp2(sim') accumulate in registers across the loop.
//  - Epilogue writes PLAIN STORES to exclusive psum slots (s = nq*2 + n-half):
//    each (s, b, col) has exactly one writer wave -> no atomics, no zero-init,
//    no same-address serialization tail (the R4 regression's cause).
// XCD swizzle: blockIdx%8 -> XCD, b = bid&3 keeps each XCD's working set
// (~2 MB) inside its 4 MB L2.
__global__ __launch_bounds__(256, 2) void k_main(const unsigned short* __restrict__ fAn,
                                                 const unsigned short* __restrict__ fBn,
                                                 float* __restrict__ psum) {
  __shared__ unsigned short sA[2][128 * 128];   // 64 KB double-buffered A chunk

  const int bid = blockIdx.x;                // 0..511
  const int x   = bid & 7;                   // XCD
  const int t   = bid >> 3;                  // 0..63
  const int b   = x & 3;
  const int nq  = (x >> 2) | ((t & 1) << 1); // 0..3
  const int mt  = t >> 1;                    // 0..31
  const int m0  = mt * 128;
  const int nbase = nq * 1024;
  const int tid = threadIdx.x;

  const int wv   = tid >> 6;
  const int lane = tid & 63;
  const int ml   = lane & 15;
  const int g    = lane >> 4;
  const int wn   = (wv & 1) * 64;    // wave n-offset within chunk
  const int wm   = (wv >> 1) * 64;   // wave m-offset within tile

  // Prologue: stage B-tile into buf1 and A-chunk 0 into buf0 concurrently.
  const unsigned short* gB  = fBn + ((size_t)b * HW + m0) * 128;
  const unsigned short* gA0 = fAn + ((size_t)b * HW + nbase) * 128;
  #pragma unroll
  for (int r = 0; r < 8; ++r) {
    int L = r * 256 + tid;
    __builtin_amdgcn_global_load_lds(
        (const __attribute__((address_space(1))) unsigned int*)(gB + (size_t)L * 8),
        (__attribute__((address_space(3))) unsigned int*)(sA[1] + L * 8), 16, 0, 0);
    __builtin_amdgcn_global_load_lds(
        (const __attribute__((address_space(1))) unsigned int*)(gA0 + (size_t)L * 8),
        (__attribute__((address_space(3))) unsigned int*)(sA[0] + L * 8), 16, 0, 0);
  }
  __syncthreads();   // both prologue stages complete

  // Hoist B fragments into registers (invariant across all 8 iters).
  short8 bfr[4][4];  // [kc][s]
  #pragma unroll
  for (int kc = 0; kc < 4; ++kc) {
    int q = kc * 4 + g;
    #pragma unroll
    for (int s = 0; s < 4; ++s) {
      int nb = wm + s * 16 + ml;
      bfr[kc][s] = *(const short8*)(sA[1] + nb * 128 + ((q ^ (nb & 7)) * 8));
    }
  }
  __syncthreads();   // all waves done reading B from buf1 -> buf1 reusable

  float colAcc[4] = {0.f, 0.f, 0.f, 0.f};

  #pragma unroll 2
  for (int it = 0; it < 8; ++it) {
    // Issue next chunk's staging FIRST (lands during this iteration's MFMAs).
    if (it < 7) {
      const unsigned short* gA = fAn + ((size_t)b * HW + nbase + (it + 1) * 128) * 128;
      unsigned short* dst = sA[(it + 1) & 1];
      #pragma unroll
      for (int r = 0; r < 8; ++r) {
        int L = r * 256 + tid;
        __builtin_amdgcn_global_load_lds(
            (const __attribute__((address_space(1))) unsigned int*)(gA + (size_t)L * 8),
            (__attribute__((address_space(3))) unsigned int*)(dst + L * 8), 16, 0, 0);
      }
    }

    const unsigned short* src = sA[it & 1];
    f32x4 acc4[4][4] = {};             // [n_sub][m_sub]
    #pragma unroll
    for (int kc = 0; kc < 4; ++kc) {
      short8 af[4];
      int q = kc * 4 + g;
      #pragma unroll
      for (int s = 0; s < 4; ++s) {
        int na = wn + s * 16 + ml;
        af[s] = *(const short8*)(src + na * 128 + ((q ^ (na & 7)) * 8));
      }
      #pragma unroll
      for (int i = 0; i < 4; ++i)
        #pragma unroll
        for (int j = 0; j < 4; ++j)
          acc4[i][j] = __builtin_amdgcn_mfma_f32_16x16x32_bf16(af[i], bfr[kc][j], acc4[i][j], 0, 0, 0);
    }
    // epilogue: accumulate exp2(sim') per column (C layout: col=lane&15,
    // row=g*4+reg). |sim'| <= 14.43 -> exp2 in [4.6e-5, 2.2e4], no shift.
    #pragma unroll
    for (int j = 0; j < 4; ++j) {
      float e = 0.f;
      #pragma unroll
      for (int i = 0; i < 4; ++i)
        #pragma unroll
        for (int r = 0; r < 4; ++r)
          e += fast_exp2(acc4[i][j][r]);
      colAcc[j] += e;
    }

    __syncthreads();   // drains the STAGE issued above; orders buffer reuse
  }

  // Cross-lane finish: lanes l, l+16, l+32, l+48 hold the 4 row-groups of
  // column j*16+l; after the two xors lane<16 holds the full 512-row partial
  // for this wave's n-half. Exclusive psum slot -> plain store.
  const int slot = nq * 2 + (wv & 1);          // 0..7
  #pragma unroll
  for (int j = 0; j < 4; ++j) {
    float e = colAcc[j];
    e += __shfl_xor(e, 16, 64);
    e += __shfl_xor(e, 32, 64);
    if (lane < 16)
      psum[(size_t)slot * (BB * HW) + (size_t)b * HW + m0 + wm + j * 16 + lane] = e;
  }
}

// K3: masked mean of (ln(sum_s psum[s]) - diag); 64 blocks, last block finishes.
__global__ __launch_bounds__(256) void k_loss(const float* __restrict__ diag,
                                              const float* __restrict__ psum,
                                              const float* __restrict__ mask,
                                              float* __restrict__ acc,
                                              float* __restrict__ out) {
  __shared__ float rn[4], rd[4];
  const int i = blockIdx.x * 256 + threadIdx.x;   // 64*256 = 16384
  float es = 0.f;
  #pragma unroll
  for (int s = 0; s < 8; ++s)
    es += psum[(size_t)s * (BB * HW) + i];
  float lse = __logf(es);                         // ln(sum exp(sim))
  float mv  = mask[i];
  float num = mv * (lse - diag[i]);
  #pragma unroll
  for (int off = 32; off; off >>= 1) {
    num += __shfl_down(num, off, 64);
    mv  += __shfl_down(mv,  off, 64);
  }
  const int lane = threadIdx.x & 63, wv = threadIdx.x >> 6;
  if (lane == 0) { rn[wv] = num; rd[wv] = mv; }
  __syncthreads();
  if (threadIdx.x == 0) {
    float n = rn[0] + rn[1] + rn[2] + rn[3];
    float d = rd[0] + rd[1] + rd[2] + rd[3];
    atomicAdd(&acc[0], n);
    atomicAdd(&acc[1], d);
    __threadfence();
    unsigned prev = atomicAdd((unsigned*)(acc + 2), 1u);
    if (prev == 63u) {   // last block: all partials visible (fence-ordered)
      float fn = atomicAdd(&acc[0], 0.f);
      float fd = atomicAdd(&acc[1], 0.f);
      out[0] = fn / (fd + 1e-6f);
    }
  }
}

extern "C" void kernel_launch(void* const* d_in, const int* in_sizes, int n_in,
                              void* d_out, int out_size, void* d_ws, size_t ws_size,
                              hipStream_t stream) {
  const float* feat_A = (const float*)d_in[0];
  const float* feat_B = (const float*)d_in[1];
  // d_in[2] = H_mat : unused by the reference computation
  const float* vmask  = (const float*)d_in[3];

  unsigned short* fAn = (unsigned short*)d_ws;            // 4 MB bf16 [b][n][c] swizzled
  unsigned short* fBn = fAn + (size_t)BB * HW * CC;       // 4 MB
  float* diag   = (float*)(fBn + (size_t)BB * HW * CC);   // 64 KB
  float* psum   = diag + BB * HW;                         // 512 KB: [8][B*HW] partials
  float* acc    = psum + 8 * BB * HW;                     // 12 B: num, den, ctr
  float* out    = (float*)d_out;

  k_prep<<<512, 256, 0, stream>>>(feat_A, feat_B, fAn, fBn, diag, acc);
  k_main<<<512, 256, 0, stream>>>(fAn, fBn, psum);
  k_loss<<<64,  256, 0, stream>>>(diag, psum, vmask, acc, out);
}